// Round 1
// baseline (10183.651 us; speedup 1.0000x reference)
//
#include <hip/hip_runtime.h>

#define N_USERS 200000
#define N_ITEMS 100000
#define NNZ     3000000
#define DIM     128

// Zero-fill d_out (harness poisons it with 0xAA before every timed call).
__global__ __launch_bounds__(256) void zero_kernel(float4* __restrict__ out, int n4) {
    int i = blockIdx.x * blockDim.x + threadIdx.x;
    if (i < n4) out[i] = make_float4(0.f, 0.f, 0.f, 0.f);
}

// One edge handled by 32 consecutive threads; lane l covers floats [4l, 4l+4).
// Coalesced float4 gathers of the two embedding rows, scalar f32 atomics out.
__global__ __launch_bounds__(256) void scatter_kernel(
    const float* __restrict__ user_emb,
    const float* __restrict__ item_emb,
    const float* __restrict__ mat_val,
    const int*   __restrict__ mat_row,
    const int*   __restrict__ mat_col,
    float* __restrict__ user_agg,
    float* __restrict__ item_agg)
{
    long long t = (long long)blockIdx.x * blockDim.x + threadIdx.x;
    int e    = (int)(t >> 5);
    int lane = (int)(t & 31);
    if (e >= NNZ) return;

    float v = mat_val[e];
    int r = mat_row[e];
    int c = mat_col[e];

    const float4* irow = (const float4*)(item_emb + (long long)c * DIM);
    const float4* urow = (const float4*)(user_emb + (long long)r * DIM);
    float4 iv = irow[lane];
    float4 uv = urow[lane];

    float* uout = user_agg + (long long)r * DIM + lane * 4;
    float* iout = item_agg + (long long)c * DIM + lane * 4;

    atomicAdd(uout + 0, v * iv.x);
    atomicAdd(uout + 1, v * iv.y);
    atomicAdd(uout + 2, v * iv.z);
    atomicAdd(uout + 3, v * iv.w);

    atomicAdd(iout + 0, v * uv.x);
    atomicAdd(iout + 1, v * uv.y);
    atomicAdd(iout + 2, v * uv.z);
    atomicAdd(iout + 3, v * uv.w);
}

extern "C" void kernel_launch(void* const* d_in, const int* in_sizes, int n_in,
                              void* d_out, int out_size, void* d_ws, size_t ws_size,
                              hipStream_t stream) {
    const float* user_emb = (const float*)d_in[0];
    const float* item_emb = (const float*)d_in[1];
    const float* mat_val  = (const float*)d_in[2];
    const int*   mat_row  = (const int*)d_in[3];
    const int*   mat_col  = (const int*)d_in[4];

    float* user_agg = (float*)d_out;                           // N_USERS*DIM floats
    float* item_agg = (float*)d_out + (long long)N_USERS * DIM; // N_ITEMS*DIM floats

    // 1) zero outputs
    int n4 = (N_USERS + N_ITEMS) * DIM / 4;   // 9,600,000
    zero_kernel<<<(n4 + 255) / 256, 256, 0, stream>>>((float4*)d_out, n4);

    // 2) scatter-add
    long long total_threads = (long long)NNZ * 32;
    int blocks = (int)((total_threads + 255) / 256);
    scatter_kernel<<<blocks, 256, 0, stream>>>(user_emb, item_emb, mat_val,
                                               mat_row, mat_col, user_agg, item_agg);
}

// Round 2
// 1405.164 us; speedup vs baseline: 7.2473x; 7.2473x over previous
//
#include <hip/hip_runtime.h>

#define N_USERS 200000
#define N_ITEMS 100000
#define NNZ     3000000
#define DIM     128
#define N_TOT   (N_USERS + N_ITEMS)            // 300000 output rows
#define CHUNK   1024
#define NB      ((N_TOT + CHUNK - 1) / CHUNK)  // 293 scan blocks

// ---------------- workspace layout ----------------
// offs:    int [N_TOT + 2]     segment offsets (exclusive scan), offs[N_TOT] = 2*NNZ
// cursors: int [N_TOT]         histogram counts, then mutable fill cursors
// bsums:   int [1024]          per-block sums for the scan
// edges:   int2[2*NNZ]         (neighbor_idx, val_bits); user segs then item segs
static const size_t WS_NEEDED =
    (size_t)(N_TOT + 2) * 4 + (size_t)N_TOT * 4 + 1024 * 4 + (size_t)2 * NNZ * 8;

// ---------------- CSR build ----------------

__global__ __launch_bounds__(256) void zero_counts(int* __restrict__ cursors) {
    int i = blockIdx.x * blockDim.x + threadIdx.x;
    if (i < N_TOT) cursors[i] = 0;
}

__global__ __launch_bounds__(256) void hist_kernel(const int* __restrict__ row,
                                                   const int* __restrict__ col,
                                                   int* __restrict__ cursors) {
    int e = blockIdx.x * blockDim.x + threadIdx.x;
    if (e >= NNZ) return;
    atomicAdd(&cursors[row[e]], 1);
    atomicAdd(&cursors[N_USERS + col[e]], 1);
}

// per-1024-chunk sum
__global__ __launch_bounds__(256) void scan1(const int* __restrict__ counts,
                                             int* __restrict__ bsums) {
    __shared__ int s[256];
    int base = blockIdx.x * CHUNK;
    int t = threadIdx.x;
    int sum = 0;
    for (int k = 0; k < 4; ++k) {
        int i = base + t * 4 + k;
        if (i < N_TOT) sum += counts[i];
    }
    s[t] = sum;
    __syncthreads();
    for (int o = 128; o > 0; o >>= 1) {
        if (t < o) s[t] += s[t + o];
        __syncthreads();
    }
    if (t == 0) bsums[blockIdx.x] = s[0];
}

// exclusive scan of block sums (single block, 512 threads >= NB)
__global__ __launch_bounds__(512) void scan2(int* __restrict__ bsums) {
    __shared__ int s[512];
    int t = threadIdx.x;
    int v = (t < NB) ? bsums[t] : 0;
    s[t] = v;
    __syncthreads();
    for (int o = 1; o < 512; o <<= 1) {
        int x = (t >= o) ? s[t - o] : 0;
        __syncthreads();
        s[t] += x;
        __syncthreads();
    }
    if (t < NB) bsums[t] = s[t] - v;   // exclusive
}

// per-chunk exclusive scan + block offset; writes offs and cursors
// NOTE: counts aliases cursors (each thread reads its elements before writing them)
__global__ __launch_bounds__(256) void scan3(const int* counts,
                                             const int* __restrict__ bsums,
                                             int* __restrict__ offs,
                                             int* cursors) {
    __shared__ int s[256];
    int base = blockIdx.x * CHUNK;
    int t = threadIdx.x;
    int c[4];
    int sum = 0;
    for (int k = 0; k < 4; ++k) {
        int i = base + t * 4 + k;
        c[k] = (i < N_TOT) ? counts[i] : 0;
        sum += c[k];
    }
    s[t] = sum;
    __syncthreads();
    for (int o = 1; o < 256; o <<= 1) {
        int x = (t >= o) ? s[t - o] : 0;
        __syncthreads();
        s[t] += x;
        __syncthreads();
    }
    int ex = s[t] - sum + bsums[blockIdx.x];
    for (int k = 0; k < 4; ++k) {
        int i = base + t * 4 + k;
        if (i < N_TOT) {
            offs[i] = ex;
            cursors[i] = ex;
            ex += c[k];
        }
    }
    if (blockIdx.x == 0 && t == 0) offs[N_TOT] = 2 * NNZ;
}

__global__ __launch_bounds__(256) void fill_kernel(const float* __restrict__ val,
                                                   const int* __restrict__ row,
                                                   const int* __restrict__ col,
                                                   int* __restrict__ cursors,
                                                   int2* __restrict__ edges) {
    int e = blockIdx.x * blockDim.x + threadIdx.x;
    if (e >= NNZ) return;
    int r = row[e], c = col[e];
    int vb = __float_as_int(val[e]);
    int p = atomicAdd(&cursors[r], 1);
    edges[p] = make_int2(c, vb);
    int q = atomicAdd(&cursors[N_USERS + c], 1);
    edges[q] = make_int2(r, vb);
}

// ---------------- gather ----------------
// One 32-lane group per output row; lane l accumulates floats [4l, 4l+4).
__global__ __launch_bounds__(256) void gather_kernel(const float* __restrict__ user_emb,
                                                     const float* __restrict__ item_emb,
                                                     const int* __restrict__ offs,
                                                     const int2* __restrict__ edges,
                                                     float* __restrict__ out) {
    int g = (blockIdx.x * blockDim.x + threadIdx.x) >> 5;
    int lane = threadIdx.x & 31;
    if (g >= N_TOT) return;

    int beg = offs[g];
    int end = offs[g + 1];
    const float* src = (g < N_USERS) ? item_emb : user_emb;

    float4 acc = make_float4(0.f, 0.f, 0.f, 0.f);
    for (int j = beg; j < end; ++j) {
        int2 e = edges[j];                      // broadcast across the group
        float v = __int_as_float(e.y);
        float4 x = ((const float4*)(src + (long long)e.x * DIM))[lane];
        acc.x += v * x.x;
        acc.y += v * x.y;
        acc.z += v * x.z;
        acc.w += v * x.w;
    }
    ((float4*)(out + (long long)g * DIM))[lane] = acc;
}

// ---------------- fallback (round-1 atomic path) ----------------

__global__ __launch_bounds__(256) void zero_out(float4* __restrict__ out, int n4) {
    int i = blockIdx.x * blockDim.x + threadIdx.x;
    if (i < n4) out[i] = make_float4(0.f, 0.f, 0.f, 0.f);
}

__global__ __launch_bounds__(256) void scatter_kernel(
    const float* __restrict__ user_emb, const float* __restrict__ item_emb,
    const float* __restrict__ mat_val, const int* __restrict__ mat_row,
    const int* __restrict__ mat_col, float* __restrict__ user_agg,
    float* __restrict__ item_agg) {
    long long t = (long long)blockIdx.x * blockDim.x + threadIdx.x;
    int e = (int)(t >> 5);
    int lane = (int)(t & 31);
    if (e >= NNZ) return;
    float v = mat_val[e];
    int r = mat_row[e], c = mat_col[e];
    float4 iv = ((const float4*)(item_emb + (long long)c * DIM))[lane];
    float4 uv = ((const float4*)(user_emb + (long long)r * DIM))[lane];
    float* uout = user_agg + (long long)r * DIM + lane * 4;
    float* iout = item_agg + (long long)c * DIM + lane * 4;
    atomicAdd(uout + 0, v * iv.x); atomicAdd(uout + 1, v * iv.y);
    atomicAdd(uout + 2, v * iv.z); atomicAdd(uout + 3, v * iv.w);
    atomicAdd(iout + 0, v * uv.x); atomicAdd(iout + 1, v * uv.y);
    atomicAdd(iout + 2, v * uv.z); atomicAdd(iout + 3, v * uv.w);
}

// ---------------- launch ----------------

extern "C" void kernel_launch(void* const* d_in, const int* in_sizes, int n_in,
                              void* d_out, int out_size, void* d_ws, size_t ws_size,
                              hipStream_t stream) {
    const float* user_emb = (const float*)d_in[0];
    const float* item_emb = (const float*)d_in[1];
    const float* mat_val  = (const float*)d_in[2];
    const int*   mat_row  = (const int*)d_in[3];
    const int*   mat_col  = (const int*)d_in[4];
    float* out = (float*)d_out;

    if (ws_size < WS_NEEDED || d_ws == nullptr) {
        // fallback: round-1 atomic scatter
        int n4 = (N_USERS + N_ITEMS) * DIM / 4;
        zero_out<<<(n4 + 255) / 256, 256, 0, stream>>>((float4*)d_out, n4);
        long long total_threads = (long long)NNZ * 32;
        int blocks = (int)((total_threads + 255) / 256);
        scatter_kernel<<<blocks, 256, 0, stream>>>(
            user_emb, item_emb, mat_val, mat_row, mat_col,
            out, out + (long long)N_USERS * DIM);
        return;
    }

    int* offs    = (int*)d_ws;             // N_TOT+2
    int* cursors = offs + (N_TOT + 2);     // N_TOT
    int* bsums   = cursors + N_TOT;        // 1024
    int2* edges  = (int2*)(bsums + 1024);  // 2*NNZ  (8B-aligned: int count is even)

    const int eb = (NNZ + 255) / 256;

    zero_counts<<<(N_TOT + 255) / 256, 256, 0, stream>>>(cursors);
    hist_kernel<<<eb, 256, 0, stream>>>(mat_row, mat_col, cursors);
    scan1<<<NB, 256, 0, stream>>>(cursors, bsums);
    scan2<<<1, 512, 0, stream>>>(bsums);
    scan3<<<NB, 256, 0, stream>>>(cursors, bsums, offs, cursors);
    fill_kernel<<<eb, 256, 0, stream>>>(mat_val, mat_row, mat_col, cursors, edges);

    long long gthreads = (long long)N_TOT * 32;
    int gblocks = (int)((gthreads + 255) / 256);
    gather_kernel<<<gblocks, 256, 0, stream>>>(user_emb, item_emb, offs, edges, out);
}